// Round 2
// baseline (6296.687 us; speedup 1.0000x reference)
//
#include <hip/hip_runtime.h>

// TdLstm: twin BasicLSTM (i,j,f,o; forget_bias=1) + final dense.
// Persistent-kernel design: 256 WGs (1/CU), W^T held in VGPRs as MFMA
// fragments for all 128 timesteps; h exchanged via L2 with per-group
// (16 WG) device-scope atomic barriers; x gathered+staged per step.
// ws usage: [0,2048) barrier counters, [4096,+1MiB) h ping-pong (bf16),
// then 1MiB final h (f32).  Total ~2.1 MiB.

using bf16x8 = __attribute__((ext_vector_type(8))) __bf16;
using f32x4  = __attribute__((ext_vector_type(4))) float;
using u32x4  = __attribute__((ext_vector_type(4))) unsigned int;
typedef unsigned short u16;

#define NT 128
#define ROWB 1664                                  // 832 k-elems * 2B per B-row
#define SWZ(row, off) ((off) ^ (((row) & 7) << 4)) // bank swizzle, 16B granules

__device__ __forceinline__ u16 f2bf(float f) {
  union { float f; unsigned u; } v; v.f = f;
  unsigned r = v.u + 0x7fffu + ((v.u >> 16) & 1u);
  return (u16)(r >> 16);
}
__device__ __forceinline__ float sigf(float x) { return 1.f / (1.f + __expf(-x)); }
__device__ __forceinline__ float tanhf_(float x) { return 2.f / (1.f + __expf(-2.f * x)) - 1.f; }

// static-index store into the A-fragment array (avoid scratch, rule #20)
__device__ __forceinline__ void setA(bf16x8* Am, int ktl, bf16x8 v) {
  switch (ktl) {
    case 0: Am[0] = v; break; case 1: Am[1] = v; break;
    case 2: Am[2] = v; break; case 3: Am[3] = v; break;
    case 4: Am[4] = v; break; case 5: Am[5] = v; break;
    case 6: Am[6] = v; break;
  }
}

template<int NKT>
__device__ __forceinline__ void mmloop(f32x4 (&acc)[8][2], const bf16x8 (&A)[8][7],
                                       int ktbase, int l, const unsigned char* sB) {
  #pragma unroll
  for (int ktl = 0; ktl < NKT; ++ktl) {
    const int kt = ktbase + ktl;
    const int kb = kt * 64 + ((l >> 4) << 4);
    const int r0 = l & 15, r1 = 16 + (l & 15);
    bf16x8 B0 = __builtin_bit_cast(bf16x8, *(const u32x4*)(sB + r0 * ROWB + SWZ(r0, kb)));
    bf16x8 B1 = __builtin_bit_cast(bf16x8, *(const u32x4*)(sB + r1 * ROWB + SWZ(r1, kb)));
    #pragma unroll
    for (int m = 0; m < 8; ++m) {
      acc[m][0] = __builtin_amdgcn_mfma_f32_16x16x32_bf16(A[m][ktl], B0, acc[m][0], 0, 0, 0);
      acc[m][1] = __builtin_amdgcn_mfma_f32_16x16x32_bf16(A[m][ktl], B1, acc[m][1], 0, 0, 0);
    }
  }
}

__global__ __launch_bounds__(256, 1) void lstm_persist(
    const int* __restrict__ lids, const int* __restrict__ rids,
    const int* __restrict__ llen, const int* __restrict__ rlen,
    const float* __restrict__ emb,
    const float* __restrict__ Wl, const float* __restrict__ bl,
    const float* __restrict__ Wr, const float* __restrict__ br,
    u16* __restrict__ hbuf,      // [2 lstm][2 buf][256][512] bf16
    float* __restrict__ hfin,    // [2 lstm][256][512] f32
    unsigned int* __restrict__ bar)
{
  __shared__ __align__(16) unsigned char sB[32 * ROWB]; // hcat staging (52 KiB)
  __shared__ __align__(16) unsigned char sR[65536];     // W-stage / K-reduction

  const int tid = threadIdx.x;
  const int w = tid >> 6, l = tid & 63;
  const int bid = blockIdx.x;
  // group (= one lstm x one 32-row b-tile, 16 WGs) pinned to one XCD
  const int xcd = bid & 7, idx = bid >> 3;
  const int grp = xcd * 2 + (idx >> 4);   // 0..15
  const int ct  = idx & 15;               // u-tile: u0 = ct*32
  const int lstm = grp >> 3, bt = grp & 7;
  const int b0 = bt * 32, u0 = ct * 32;

  const int*   ids  = lstm ? rids : lids;
  const int*   lenp = lstm ? rlen : llen;
  const float* W    = lstm ? Wr : Wl;
  const float* bv   = lstm ? br : bl;

  // K layout (Kpad=832): [0,300) = x rows of W, [300,320) = zero pad, [320,832) = h rows
  const int ktbase = (w == 0) ? 0 : (w == 1) ? 7 : (w == 2) ? 13 : 20;
  const int nkt    = (w == 0) ? 7 : (w == 1) ? 6 : (w == 2) ? 7 : 6;

  // ---- one-time: build W^T A-fragments in registers (coalesced via LDS) ----
  bf16x8 A[8][7];
  for (int kc = 0; kc < 13; ++kc) {        // 13 chunks of 64 k-rows
    float* sW = (float*)sR;                // [4 g][64 r][32 c] = 8192 floats
    for (int i = 0; i < 32; ++i) {         // 32*256 = 8192 elements (was 8: BUG)
      int id2 = tid + i * 256;
      int c = id2 & 31, r = (id2 >> 5) & 63, g = id2 >> 11;
      int kk = kc * 64 + r;
      float v = 0.f;
      if (kk < 300)       v = W[kk * 2048 + g * 512 + u0 + c];
      else if (kk >= 320) v = W[(kk - 20) * 2048 + g * 512 + u0 + c];
      sW[(g * 64 + r) * 32 + c] = v;
    }
    __syncthreads();
    #pragma unroll
    for (int kt2 = 0; kt2 < 2; ++kt2) {
      int kt = kc * 2 + kt2;
      int ktl = kt - ktbase;
      if (ktl >= 0 && ktl < nkt) {
        #pragma unroll
        for (int m = 0; m < 8; ++m) {
          int rho = m * 16 + (l & 15);     // A-row; col map rho = du*4 + g
          int du = rho >> 2, g = rho & 3;
          union { u16 s[8]; bf16x8 v; } tmp;
          #pragma unroll
          for (int j = 0; j < 8; ++j) {
            int k  = kt * 32 + ((l >> 4) << 3) + j;
            int kr = k - kc * 64;
            tmp.s[j] = f2bf(sW[(g * 64 + kr) * 32 + du]);
          }
          setA(A[m], ktl, tmp.v);
        }
      }
    }
    __syncthreads();
  }

  // zero-pad x region k in [300,320) of sB (never rewritten)
  if (tid < 160) {
    int row = tid / 5, c5 = tid - (tid / 5) * 5;
    *(unsigned long long*)(sB + row * ROWB + SWZ(row, 600 + c5 * 8)) = 0ULL;
  }

  int lenn[2];
  lenn[0] = lenp[b0 + (l & 15)];
  lenn[1] = lenp[b0 + 16 + (l & 15)];
  float bia[2][4];
  #pragma unroll
  for (int mi = 0; mi < 2; ++mi) {
    int du = w * 8 + mi * 4 + (l >> 4);
    #pragma unroll
    for (int g = 0; g < 4; ++g) bia[mi][g] = bv[g * 512 + u0 + du];
  }
  float cst[2][2] = {{0.f, 0.f}, {0.f, 0.f}};
  float hst[2][2] = {{0.f, 0.f}, {0.f, 0.f}};

  for (int t = 0; t < NT; ++t) {
    // stage x(t): gather 32 emb rows (f32) -> bf16 -> sB[k<300]
    #pragma unroll
    for (int i = 0; i < 10; ++i) {
      int id2 = tid + i * 256;
      if (id2 < 2400) {
        int row = id2 / 75, f4 = id2 - (id2 / 75) * 75;
        int eid = ids[(b0 + row) * NT + t];
        float4 xv = *(const float4*)(emb + eid * 300 + f4 * 4);
        unsigned long long pk =
            (unsigned long long)f2bf(xv.x) |
            ((unsigned long long)f2bf(xv.y) << 16) |
            ((unsigned long long)f2bf(xv.z) << 32) |
            ((unsigned long long)f2bf(xv.w) << 48);
        *(unsigned long long*)(sB + row * ROWB + SWZ(row, f4 * 8)) = pk;
      }
    }
    // stage h(t-1) from global ping-pong buffer (zeros at t==0)
    const u16* hsrc = hbuf + (((lstm * 2 + ((t & 1) ^ 1)) * 256) + b0) * 512;
    #pragma unroll
    for (int i = 0; i < 8; ++i) {
      int id2 = tid + i * 256;
      int row = id2 >> 6, kc2 = id2 & 63;
      u32x4 hv = {0u, 0u, 0u, 0u};
      if (t > 0) hv = *(const u32x4*)(hsrc + row * 512 + kc2 * 8);
      *(u32x4*)(sB + row * ROWB + SWZ(row, 640 + kc2 * 16)) = hv;
    }
    __syncthreads();

    f32x4 acc[8][2];
    #pragma unroll
    for (int m = 0; m < 8; ++m) {
      acc[m][0] = {0.f, 0.f, 0.f, 0.f};
      acc[m][1] = {0.f, 0.f, 0.f, 0.f};
    }
    if (nkt == 7) mmloop<7>(acc, A, ktbase, l, sB);
    else          mmloop<6>(acc, A, ktbase, l, sB);

    // cross-wave K reduction
    #pragma unroll
    for (int m = 0; m < 8; ++m)
      #pragma unroll
      for (int n = 0; n < 2; ++n)
        *(f32x4*)(sR + (((w * 8 + m) * 2 + n) * 64 + l) * 16) = acc[m][n];
    __syncthreads();

    #pragma unroll
    for (int mi = 0; mi < 2; ++mi) {
      const int m = w * 2 + mi;           // this wave finalizes M-tiles 2w,2w+1
      #pragma unroll
      for (int n = 0; n < 2; ++n) {
        f32x4 z = {0.f, 0.f, 0.f, 0.f};
        #pragma unroll
        for (int v = 0; v < 4; ++v)
          z += *(const f32x4*)(sR + (((v * 8 + m) * 2 + n) * 64 + l) * 16);
        // acc reg r == gate r for cell (b,u): i,j,f,o
        float zi = z[0] + bia[mi][0];
        float zj = z[1] + bia[mi][1];
        float zf = z[2] + bia[mi][2];
        float zo = z[3] + bia[mi][3];
        float cn = cst[mi][n] * sigf(zf + 1.f) + sigf(zi) * tanhf_(zj);
        float hn = tanhf_(cn) * sigf(zo);
        if (t < lenn[n]) { cst[mi][n] = cn; hst[mi][n] = hn; }
        int bb = b0 + n * 16 + (l & 15);
        int uu = u0 + w * 8 + mi * 4 + (l >> 4);
        hbuf[(((lstm * 2 + (t & 1)) * 256) + bb) * 512 + uu] = f2bf(hst[mi][n]);
      }
    }

    // group barrier (16 WGs), device-scope
    __threadfence();
    __syncthreads();
    if (tid == 0) {
      atomicAdd(&bar[grp * 32], 1u);
      unsigned target = 16u * (unsigned)(t + 1);
      while (__hip_atomic_load(&bar[grp * 32], __ATOMIC_RELAXED,
                               __HIP_MEMORY_SCOPE_AGENT) < target)
        __builtin_amdgcn_s_sleep(8);
    }
    __syncthreads();
    __threadfence();
  }

  #pragma unroll
  for (int mi = 0; mi < 2; ++mi)
    #pragma unroll
    for (int n = 0; n < 2; ++n) {
      int bb = b0 + n * 16 + (l & 15);
      int uu = u0 + w * 8 + mi * 4 + (l >> 4);
      hfin[lstm * (256 * 512) + bb * 512 + uu] = hst[mi][n];
    }
}

__global__ void dense_out(const float* __restrict__ hfin,
                          const float* __restrict__ Wd, const float* __restrict__ bd,
                          float* __restrict__ out) {
  const int b = blockIdx.x, l = threadIdx.x;
  float a0 = 0.f, a1 = 0.f, a2 = 0.f;
  for (int i = l; i < 1024; i += 64) {
    float hv = (i < 512) ? hfin[b * 512 + i] : hfin[256 * 512 + b * 512 + (i - 512)];
    a0 += hv * Wd[i * 3 + 0];
    a1 += hv * Wd[i * 3 + 1];
    a2 += hv * Wd[i * 3 + 2];
  }
  #pragma unroll
  for (int off = 32; off > 0; off >>= 1) {
    a0 += __shfl_down(a0, off);
    a1 += __shfl_down(a1, off);
    a2 += __shfl_down(a2, off);
  }
  if (l == 0) {
    out[b * 3 + 0] = a0 + bd[0];
    out[b * 3 + 1] = a1 + bd[1];
    out[b * 3 + 2] = a2 + bd[2];
  }
}

extern "C" void kernel_launch(void* const* d_in, const int* in_sizes, int n_in,
                              void* d_out, int out_size, void* d_ws, size_t ws_size,
                              hipStream_t stream) {
  const int*   lids = (const int*)d_in[0];
  const int*   rids = (const int*)d_in[1];
  const int*   llen = (const int*)d_in[2];
  const int*   rlen = (const int*)d_in[3];
  const float* emb  = (const float*)d_in[4];
  const float* Wl   = (const float*)d_in[5];
  const float* bl   = (const float*)d_in[6];
  const float* Wr   = (const float*)d_in[7];
  const float* br   = (const float*)d_in[8];
  const float* Wd   = (const float*)d_in[9];
  const float* bd   = (const float*)d_in[10];

  unsigned char* ws = (unsigned char*)d_ws;
  unsigned int* bar = (unsigned int*)ws;             // 16 groups * 128B
  u16*   hbuf = (u16*)(ws + 4096);                   // 1 MiB
  float* hfin = (float*)(ws + 4096 + (1u << 20));    // 1 MiB

  hipMemsetAsync(bar, 0, 2048, stream);              // re-arm barrier each call
  hipLaunchKernelGGL(lstm_persist, dim3(256), dim3(256), 0, stream,
                     lids, rids, llen, rlen, emb, Wl, bl, Wr, br, hbuf, hfin, bar);
  hipLaunchKernelGGL(dense_out, dim3(256), dim3(64), 0, stream,
                     hfin, Wd, bd, (float*)d_out);
}

// Round 3
// 1609.701 us; speedup vs baseline: 3.9117x; 3.9117x over previous
//
#include <hip/hip_runtime.h>

// TdLstm: twin BasicLSTM (i,j,f,o; forget_bias=1) + final dense.
// Persistent-kernel design: 256 WGs (1/CU), W^T held in VGPRs as MFMA
// fragments for all 128 timesteps; h exchanged via L3 (sc0/sc1 write-through
// atomics, NO L2 fences) with per-group (16 WG) relaxed atomic barriers.
// ws usage: [0,2048) barrier counters, [4096,+1MiB) h ping-pong (bf16),
// then 1MiB final h (f32).

using bf16x8 = __attribute__((ext_vector_type(8))) __bf16;
using f32x4  = __attribute__((ext_vector_type(4))) float;
using u32x4  = __attribute__((ext_vector_type(4))) unsigned int;
typedef unsigned short u16;
typedef unsigned long long u64;

#define NT 128
#define ROWB 1664                                  // 832 k-elems * 2B per B-row
#define SWZ(row, off) ((off) ^ (((row) & 7) << 4)) // bank swizzle, 16B granules

__device__ __forceinline__ u16 f2bf(float f) {
  union { float f; unsigned u; } v; v.f = f;
  unsigned r = v.u + 0x7fffu + ((v.u >> 16) & 1u);
  return (u16)(r >> 16);
}
__device__ __forceinline__ float sigf(float x) { return 1.f / (1.f + __expf(-x)); }
__device__ __forceinline__ float tanhf_(float x) { return 2.f / (1.f + __expf(-2.f * x)) - 1.f; }

// static-index store into the A-fragment array (avoid scratch, rule #20)
__device__ __forceinline__ void setA(bf16x8* Am, int ktl, bf16x8 v) {
  switch (ktl) {
    case 0: Am[0] = v; break; case 1: Am[1] = v; break;
    case 2: Am[2] = v; break; case 3: Am[3] = v; break;
    case 4: Am[4] = v; break; case 5: Am[5] = v; break;
    case 6: Am[6] = v; break;
  }
}

template<int NKT>
__device__ __forceinline__ void mmloop(f32x4 (&acc)[8][2], const bf16x8 (&A)[8][7],
                                       int ktbase, int l, const unsigned char* sB) {
  #pragma unroll
  for (int ktl = 0; ktl < NKT; ++ktl) {
    const int kt = ktbase + ktl;
    const int kb = kt * 64 + ((l >> 4) << 4);
    const int r0 = l & 15, r1 = 16 + (l & 15);
    bf16x8 B0 = __builtin_bit_cast(bf16x8, *(const u32x4*)(sB + r0 * ROWB + SWZ(r0, kb)));
    bf16x8 B1 = __builtin_bit_cast(bf16x8, *(const u32x4*)(sB + r1 * ROWB + SWZ(r1, kb)));
    #pragma unroll
    for (int m = 0; m < 8; ++m) {
      acc[m][0] = __builtin_amdgcn_mfma_f32_16x16x32_bf16(A[m][ktl], B0, acc[m][0], 0, 0, 0);
      acc[m][1] = __builtin_amdgcn_mfma_f32_16x16x32_bf16(A[m][ktl], B1, acc[m][1], 0, 0, 0);
    }
  }
}

__global__ __launch_bounds__(256, 1) void lstm_persist(
    const int* __restrict__ lids, const int* __restrict__ rids,
    const int* __restrict__ llen, const int* __restrict__ rlen,
    const float* __restrict__ emb,
    const float* __restrict__ Wl, const float* __restrict__ bl,
    const float* __restrict__ Wr, const float* __restrict__ br,
    u64* __restrict__ hbuf,      // [2 lstm][2 buf][256][128] u64 (bf16 x4)
    float* __restrict__ hfin,    // [2 lstm][256][512] f32
    unsigned int* __restrict__ bar)
{
  __shared__ __align__(16) unsigned char sB[32 * ROWB]; // hcat staging (52 KiB)
  __shared__ __align__(16) unsigned char sR[65536];     // W-stage / K-reduction
  __shared__ __align__(8)  u16 sH[32][36];              // h-out staging (2.25 KiB)

  const int tid = threadIdx.x;
  const int w = tid >> 6, l = tid & 63;
  const int bid = blockIdx.x;
  // group (= one lstm x one 32-row b-tile, 16 WGs); bid&7 aims at one XCD
  const int xcd = bid & 7, idx = bid >> 3;
  const int grp = xcd * 2 + (idx >> 4);   // 0..15
  const int ct  = idx & 15;               // u-tile: u0 = ct*32
  const int lstm = grp >> 3, bt = grp & 7;
  const int b0 = bt * 32, u0 = ct * 32;

  const int*   ids  = lstm ? rids : lids;
  const int*   lenp = lstm ? rlen : llen;
  const float* W    = lstm ? Wr : Wl;
  const float* bv   = lstm ? br : bl;

  // K layout (Kpad=832): [0,300) = x rows of W, [300,320) = zero pad, [320,832) = h rows
  const int ktbase = (w == 0) ? 0 : (w == 1) ? 7 : (w == 2) ? 13 : 20;
  const int nkt    = (w == 0) ? 7 : (w == 1) ? 6 : (w == 2) ? 7 : 6;

  // ---- one-time: build W^T A-fragments in registers (coalesced via LDS) ----
  bf16x8 A[8][7];
  for (int kc = 0; kc < 13; ++kc) {        // 13 chunks of 64 k-rows
    float* sW = (float*)sR;                // [4 g][64 r][32 c] = 8192 floats
    for (int i = 0; i < 32; ++i) {
      int id2 = tid + i * 256;
      int c = id2 & 31, r = (id2 >> 5) & 63, g = id2 >> 11;
      int kk = kc * 64 + r;
      float v = 0.f;
      if (kk < 300)       v = W[kk * 2048 + g * 512 + u0 + c];
      else if (kk >= 320) v = W[(kk - 20) * 2048 + g * 512 + u0 + c];
      sW[(g * 64 + r) * 32 + c] = v;
    }
    __syncthreads();
    #pragma unroll
    for (int kt2 = 0; kt2 < 2; ++kt2) {
      int kt = kc * 2 + kt2;
      int ktl = kt - ktbase;
      if (ktl >= 0 && ktl < nkt) {
        #pragma unroll
        for (int m = 0; m < 8; ++m) {
          int rho = m * 16 + (l & 15);     // A-row; col map rho = du*4 + g
          int du = rho >> 2, g = rho & 3;
          union { u16 s[8]; bf16x8 v; } tmp;
          #pragma unroll
          for (int j = 0; j < 8; ++j) {
            int k  = kt * 32 + ((l >> 4) << 3) + j;
            int kr = k - kc * 64;
            tmp.s[j] = f2bf(sW[(g * 64 + kr) * 32 + du]);
          }
          setA(A[m], ktl, tmp.v);
        }
      }
    }
    __syncthreads();
  }

  // zero-pad x region k in [300,320) of sB (never rewritten)
  if (tid < 160) {
    int row = tid / 5, c5 = tid - (tid / 5) * 5;
    *(u64*)(sB + row * ROWB + SWZ(row, 600 + c5 * 8)) = 0ULL;
  }

  int lenn[2];
  lenn[0] = lenp[b0 + (l & 15)];
  lenn[1] = lenp[b0 + 16 + (l & 15)];
  float bia[2][4];
  #pragma unroll
  for (int mi = 0; mi < 2; ++mi) {
    int du = w * 8 + mi * 4 + (l >> 4);
    #pragma unroll
    for (int g = 0; g < 4; ++g) bia[mi][g] = bv[g * 512 + u0 + du];
  }
  float cst[2][2] = {{0.f, 0.f}, {0.f, 0.f}};
  float hst[2][2] = {{0.f, 0.f}, {0.f, 0.f}};

  for (int t = 0; t < NT; ++t) {
    // stage x(t): gather 32 emb rows (f32) -> bf16 -> sB[k<300]
    #pragma unroll
    for (int i = 0; i < 10; ++i) {
      int id2 = tid + i * 256;
      if (id2 < 2400) {
        int row = id2 / 75, f4 = id2 - (id2 / 75) * 75;
        int eid = ids[(b0 + row) * NT + t];
        float4 xv = *(const float4*)(emb + eid * 300 + f4 * 4);
        u64 pk = (u64)f2bf(xv.x) | ((u64)f2bf(xv.y) << 16) |
                 ((u64)f2bf(xv.z) << 32) | ((u64)f2bf(xv.w) << 48);
        *(u64*)(sB + row * ROWB + SWZ(row, f4 * 8)) = pk;
      }
    }
    // stage h(t-1): L3-coherent u64 loads (sc0/sc1, bypass L1/L2)
    const u64* hsrc = hbuf + (((lstm * 2 + ((t & 1) ^ 1)) * 256) + b0) * 128;
    #pragma unroll
    for (int i = 0; i < 16; ++i) {
      int id2 = tid + i * 256;
      int row = id2 >> 7, c8 = id2 & 127;
      u64 hv = 0ULL;
      if (t > 0)
        hv = __hip_atomic_load(&hsrc[row * 128 + c8], __ATOMIC_RELAXED,
                               __HIP_MEMORY_SCOPE_AGENT);
      *(u64*)(sB + row * ROWB + SWZ(row, 640 + c8 * 8)) = hv;
    }
    __syncthreads();

    f32x4 acc[8][2];
    #pragma unroll
    for (int m = 0; m < 8; ++m) {
      acc[m][0] = {0.f, 0.f, 0.f, 0.f};
      acc[m][1] = {0.f, 0.f, 0.f, 0.f};
    }
    if (nkt == 7) mmloop<7>(acc, A, ktbase, l, sB);
    else          mmloop<6>(acc, A, ktbase, l, sB);

    // cross-wave K reduction
    #pragma unroll
    for (int m = 0; m < 8; ++m)
      #pragma unroll
      for (int n = 0; n < 2; ++n)
        *(f32x4*)(sR + (((w * 8 + m) * 2 + n) * 64 + l) * 16) = acc[m][n];
    __syncthreads();

    #pragma unroll
    for (int mi = 0; mi < 2; ++mi) {
      const int m = w * 2 + mi;           // this wave finalizes M-tiles 2w,2w+1
      #pragma unroll
      for (int n = 0; n < 2; ++n) {
        f32x4 z = {0.f, 0.f, 0.f, 0.f};
        #pragma unroll
        for (int v = 0; v < 4; ++v)
          z += *(const f32x4*)(sR + (((v * 8 + m) * 2 + n) * 64 + l) * 16);
        // acc reg r == gate r for cell (b,u): i,j,f,o
        float zi = z[0] + bia[mi][0];
        float zj = z[1] + bia[mi][1];
        float zf = z[2] + bia[mi][2];
        float zo = z[3] + bia[mi][3];
        float cn = cst[mi][n] * sigf(zf + 1.f) + sigf(zi) * tanhf_(zj);
        float hn = tanhf_(cn) * sigf(zo);
        if (t < lenn[n]) { cst[mi][n] = cn; hst[mi][n] = hn; }
        sH[n * 16 + (l & 15)][w * 8 + mi * 4 + (l >> 4)] = f2bf(hst[mi][n]);
      }
    }
    __syncthreads();   // sH complete; sR reads done

    // h-out: one coalesced u64 (4x bf16) sc0/sc1 store per thread to L3
    {
      int bbL = tid >> 3, u8 = tid & 7;
      u64 pk = (u64)sH[bbL][u8 * 4] | ((u64)sH[bbL][u8 * 4 + 1] << 16) |
               ((u64)sH[bbL][u8 * 4 + 2] << 32) | ((u64)sH[bbL][u8 * 4 + 3] << 48);
      u64* hdst = hbuf + (((lstm * 2 + (t & 1)) * 256) + b0 + bbL) * 128 + (u0 >> 2) + u8;
      __hip_atomic_store(hdst, pk, __ATOMIC_RELAXED, __HIP_MEMORY_SCOPE_AGENT);
    }
    __syncthreads();   // drains vmcnt(0) on every thread -> h visible at L3

    // group barrier (16 WGs), relaxed agent atomics (no L2 fences!)
    if (tid == 0) {
      __hip_atomic_fetch_add(&bar[grp * 32], 1u, __ATOMIC_RELAXED,
                             __HIP_MEMORY_SCOPE_AGENT);
      unsigned target = 16u * (unsigned)(t + 1);
      while (__hip_atomic_load(&bar[grp * 32], __ATOMIC_RELAXED,
                               __HIP_MEMORY_SCOPE_AGENT) < target)
        __builtin_amdgcn_s_sleep(4);
    }
    __syncthreads();
  }

  #pragma unroll
  for (int mi = 0; mi < 2; ++mi)
    #pragma unroll
    for (int n = 0; n < 2; ++n) {
      int bb = b0 + n * 16 + (l & 15);
      int uu = u0 + w * 8 + mi * 4 + (l >> 4);
      hfin[lstm * (256 * 512) + bb * 512 + uu] = hst[mi][n];
    }
}

__global__ void dense_out(const float* __restrict__ hfin,
                          const float* __restrict__ Wd, const float* __restrict__ bd,
                          float* __restrict__ out) {
  const int b = blockIdx.x, l = threadIdx.x;
  float a0 = 0.f, a1 = 0.f, a2 = 0.f;
  for (int i = l; i < 1024; i += 64) {
    float hv = (i < 512) ? hfin[b * 512 + i] : hfin[256 * 512 + b * 512 + (i - 512)];
    a0 += hv * Wd[i * 3 + 0];
    a1 += hv * Wd[i * 3 + 1];
    a2 += hv * Wd[i * 3 + 2];
  }
  #pragma unroll
  for (int off = 32; off > 0; off >>= 1) {
    a0 += __shfl_down(a0, off);
    a1 += __shfl_down(a1, off);
    a2 += __shfl_down(a2, off);
  }
  if (l == 0) {
    out[b * 3 + 0] = a0 + bd[0];
    out[b * 3 + 1] = a1 + bd[1];
    out[b * 3 + 2] = a2 + bd[2];
  }
}

extern "C" void kernel_launch(void* const* d_in, const int* in_sizes, int n_in,
                              void* d_out, int out_size, void* d_ws, size_t ws_size,
                              hipStream_t stream) {
  const int*   lids = (const int*)d_in[0];
  const int*   rids = (const int*)d_in[1];
  const int*   llen = (const int*)d_in[2];
  const int*   rlen = (const int*)d_in[3];
  const float* emb  = (const float*)d_in[4];
  const float* Wl   = (const float*)d_in[5];
  const float* bl   = (const float*)d_in[6];
  const float* Wr   = (const float*)d_in[7];
  const float* br   = (const float*)d_in[8];
  const float* Wd   = (const float*)d_in[9];
  const float* bd   = (const float*)d_in[10];

  unsigned char* ws = (unsigned char*)d_ws;
  unsigned int* bar = (unsigned int*)ws;             // 16 groups * 128B
  u64*   hbuf = (u64*)(ws + 4096);                   // 1 MiB
  float* hfin = (float*)(ws + 4096 + (1u << 20));    // 1 MiB

  hipMemsetAsync(bar, 0, 2048, stream);              // re-arm barrier each call
  hipLaunchKernelGGL(lstm_persist, dim3(256), dim3(256), 0, stream,
                     lids, rids, llen, rlen, emb, Wl, bl, Wr, br, hbuf, hfin, bar);
  hipLaunchKernelGGL(dense_out, dim3(256), dim3(64), 0, stream,
                     hfin, Wd, bd, (float*)d_out);
}

// Round 4
// 718.657 us; speedup vs baseline: 8.7617x; 2.2399x over previous
//
#include <hip/hip_runtime.h>

// TdLstm: twin BasicLSTM (i,j,f,o; forget_bias=1) + final dense.
// Persistent kernel, 256 WGs (1/CU). W^T in VGPRs (A[2][26] frags/wave,
// M-split across waves -> no cross-wave reduction). x(t+1) prefetched into
// registers each step (ids preloaded in LDS); h exchanged via L3 sc0/sc1
// atomics; raw s_barrier + lgkmcnt-only waits keep prefetch in flight.

using bf16x8 = __attribute__((ext_vector_type(8))) __bf16;
using f32x4  = __attribute__((ext_vector_type(4))) float;
using u32x4  = __attribute__((ext_vector_type(4))) unsigned int;
typedef unsigned short u16;
typedef unsigned long long u64;

#define NT 128
#define ROWB 1664                                  // 832 k-elems * 2B per B-row
#define SWZ(row, off) ((off) ^ (((row) & 7) << 4)) // bank swizzle, 16B granules

#define LGKM0  asm volatile("s_waitcnt lgkmcnt(0)" ::: "memory")
#define VM0    asm volatile("s_waitcnt vmcnt(0)" ::: "memory")
#define BAR()  __builtin_amdgcn_s_barrier()
#define SCHED0 __builtin_amdgcn_sched_barrier(0)

__device__ __forceinline__ u16 f2bf(float f) {
  union { float f; unsigned u; } v; v.f = f;
  unsigned r = v.u + 0x7fffu + ((v.u >> 16) & 1u);
  return (u16)(r >> 16);
}
__device__ __forceinline__ float sigf(float x) { return 1.f / (1.f + __expf(-x)); }
__device__ __forceinline__ float tanhf_(float x) { return 2.f / (1.f + __expf(-2.f * x)) - 1.f; }

// static-index store into A-fragment array (avoid scratch, rule #20)
__device__ __forceinline__ void setA26(bf16x8 (&A)[26], int kt, bf16x8 v) {
  switch (kt) {
    case 0:A[0]=v;break;  case 1:A[1]=v;break;  case 2:A[2]=v;break;
    case 3:A[3]=v;break;  case 4:A[4]=v;break;  case 5:A[5]=v;break;
    case 6:A[6]=v;break;  case 7:A[7]=v;break;  case 8:A[8]=v;break;
    case 9:A[9]=v;break;  case 10:A[10]=v;break; case 11:A[11]=v;break;
    case 12:A[12]=v;break; case 13:A[13]=v;break; case 14:A[14]=v;break;
    case 15:A[15]=v;break; case 16:A[16]=v;break; case 17:A[17]=v;break;
    case 18:A[18]=v;break; case 19:A[19]=v;break; case 20:A[20]=v;break;
    case 21:A[21]=v;break; case 22:A[22]=v;break; case 23:A[23]=v;break;
    case 24:A[24]=v;break; case 25:A[25]=v;break;
  }
}

__global__ __launch_bounds__(256, 1) void lstm_persist(
    const int* __restrict__ lids, const int* __restrict__ rids,
    const int* __restrict__ llen, const int* __restrict__ rlen,
    const float* __restrict__ emb,
    const float* __restrict__ Wl, const float* __restrict__ bl,
    const float* __restrict__ Wr, const float* __restrict__ br,
    u64* __restrict__ hbuf,      // [2 lstm][2 buf][256][128] u64 (bf16 x4)
    float* __restrict__ hfin,    // [2 lstm][256][512] f32
    unsigned int* __restrict__ bar)
{
  __shared__ __align__(16) unsigned char sB[32 * ROWB]; // 52 KiB (also W scratch)
  __shared__ __align__(8)  u16 sH[32][36];              // h-out staging
  __shared__ int sI[4096];                              // ids[32 rows][128 t]

  const int tid = threadIdx.x;
  const int w = tid >> 6, l = tid & 63;
  const int bid = blockIdx.x;
  const int xcd = bid & 7, idx = bid >> 3;
  const int grp = xcd * 2 + (idx >> 4);   // 0..15 (lstm x b-tile)
  const int ct  = idx & 15;               // u-tile: u0 = ct*32
  const int lstm = grp >> 3, bt = grp & 7;
  const int b0 = bt * 32, u0 = ct * 32;

  const int*   ids  = lstm ? rids : lids;
  const int*   lenp = lstm ? rlen : llen;
  const float* W    = lstm ? Wr : Wl;
  const float* bv   = lstm ? br : bl;

  // ---- one-time: build W^T A-fragments (M-split: wave w owns mf=2w,2w+1) ----
  bf16x8 A0[26], A1[26];
  {
    float* sW = (float*)sB;                // [4 g][64 r][32 c] = 32 KiB scratch
    for (int kc = 0; kc < 13; ++kc) {
      for (int i = 0; i < 32; ++i) {
        int id2 = tid + i * 256;
        int c = id2 & 31, r = (id2 >> 5) & 63, g = id2 >> 11;
        int kk = kc * 64 + r;
        float v = 0.f;
        if (kk < 300)       v = W[kk * 2048 + g * 512 + u0 + c];
        else if (kk >= 320) v = W[(kk - 20) * 2048 + g * 512 + u0 + c];
        sW[(g * 64 + r) * 32 + c] = v;
      }
      __syncthreads();
      #pragma unroll
      for (int kt2 = 0; kt2 < 2; ++kt2) {
        int kt = kc * 2 + kt2;
        #pragma unroll
        for (int mf2 = 0; mf2 < 2; ++mf2) {
          int mf = w * 2 + mf2;
          int rho = mf * 16 + (l & 15);    // col map rho = du*4 + g
          int du = rho >> 2, g = rho & 3;
          union { u16 s[8]; bf16x8 v; } tmp;
          #pragma unroll
          for (int j = 0; j < 8; ++j) {
            int kr = kt2 * 32 + ((l >> 4) << 3) + j;   // within 64-row chunk
            tmp.s[j] = f2bf(sW[(g * 64 + kr) * 32 + du]);
          }
          if (mf2 == 0) setA26(A0, kt, tmp.v); else setA26(A1, kt, tmp.v);
        }
      }
      __syncthreads();
    }
  }

  // zero-pad x region k in [300,320)
  if (tid < 160) {
    int row = tid / 5, c5 = tid - (tid / 5) * 5;
    *(u64*)(sB + row * ROWB + SWZ(row, 600 + c5 * 8)) = 0ULL;
  }
  // preload ids for this b-tile: 4096 contiguous ints
  {
    const int* src = ids + b0 * NT;
    #pragma unroll
    for (int i = 0; i < 4; ++i)
      *(int4*)&sI[(tid + i * 256) * 4] = *(const int4*)&src[(tid + i * 256) * 4];
  }
  __syncthreads();

  // per-thread gather coords (precomputed)
  int ldsoff[10], sirow[10], foff[10];
  #pragma unroll
  for (int i = 0; i < 10; ++i) {
    int id2 = tid + i * 256;
    int row = id2 / 75, f4 = id2 - row * 75;
    ldsoff[i] = row * ROWB + SWZ(row, f4 * 8);
    sirow[i]  = row * NT;
    foff[i]   = f4 * 4;
  }
  int hoff[16];
  #pragma unroll
  for (int i = 0; i < 16; ++i) {
    int id2 = tid + i * 256;
    int row = id2 >> 7, c8 = id2 & 127;
    hoff[i] = row * ROWB + SWZ(row, 640 + c8 * 8);
  }

  int lenn[2];
  lenn[0] = lenp[b0 + (l & 15)];
  lenn[1] = lenp[b0 + 16 + (l & 15)];
  float bia[2][4];
  #pragma unroll
  for (int mf2 = 0; mf2 < 2; ++mf2) {
    int du = w * 8 + mf2 * 4 + (l >> 4);
    #pragma unroll
    for (int g = 0; g < 4; ++g) bia[mf2][g] = bv[g * 512 + u0 + du];
  }
  float cst[2][2] = {{0.f, 0.f}, {0.f, 0.f}};
  float hst[2][2] = {{0.f, 0.f}, {0.f, 0.f}};

  // prologue: prefetch x(0)
  float4 px[10];
  #pragma unroll
  for (int i = 0; i < 10; ++i)
    if (i < 9 || tid < 96) {
      int eid = sI[sirow[i]];
      px[i] = *(const float4*)(emb + eid * 300 + foff[i]);
    }

  const int r0 = l & 15, r1 = 16 + (l & 15);

  for (int t = 0; t < NT; ++t) {
    // 1. issue h(t-1) loads (L3-coherent)
    u64 hld[16];
    const u64* hsrc = hbuf + (((lstm * 2 + ((t & 1) ^ 1)) * 256) + b0) * 128;
    #pragma unroll
    for (int i = 0; i < 16; ++i) {
      u64 v = 0ULL;
      if (t > 0)
        v = __hip_atomic_load(&hsrc[tid + i * 256], __ATOMIC_RELAXED,
                              __HIP_MEMORY_SCOPE_AGENT);
      hld[i] = v;
    }
    // 2. write x(t) from prefetch regs -> LDS
    #pragma unroll
    for (int i = 0; i < 10; ++i)
      if (i < 9 || tid < 96) {
        float4 xv = px[i];
        u64 pk = (u64)f2bf(xv.x) | ((u64)f2bf(xv.y) << 16) |
                 ((u64)f2bf(xv.z) << 32) | ((u64)f2bf(xv.w) << 48);
        *(u64*)(sB + ldsoff[i]) = pk;
      }
    // 3. issue x(t+1) prefetch (stays in flight across raw barriers)
    {
      int tn = (t + 1) & (NT - 1);
      #pragma unroll
      for (int i = 0; i < 10; ++i)
        if (i < 9 || tid < 96) {
          int eid = sI[sirow[i] + tn];
          px[i] = *(const float4*)(emb + eid * 300 + foff[i]);
        }
    }
    // 4. h(t-1) -> LDS
    #pragma unroll
    for (int i = 0; i < 16; ++i) *(u64*)(sB + hoff[i]) = hld[i];

    LGKM0; BAR(); SCHED0;

    // 5. GEMM: 26 kt x (2 mf x 2 n) MFMA, acc is final (M-split)
    f32x4 acc[2][2];
    acc[0][0] = {0.f,0.f,0.f,0.f}; acc[0][1] = {0.f,0.f,0.f,0.f};
    acc[1][0] = {0.f,0.f,0.f,0.f}; acc[1][1] = {0.f,0.f,0.f,0.f};
    #pragma unroll
    for (int kt = 0; kt < 26; ++kt) {
      int kb = kt * 64 + ((l >> 4) << 4);
      bf16x8 B0 = __builtin_bit_cast(bf16x8, *(const u32x4*)(sB + r0 * ROWB + SWZ(r0, kb)));
      bf16x8 B1 = __builtin_bit_cast(bf16x8, *(const u32x4*)(sB + r1 * ROWB + SWZ(r1, kb)));
      acc[0][0] = __builtin_amdgcn_mfma_f32_16x16x32_bf16(A0[kt], B0, acc[0][0], 0, 0, 0);
      acc[0][1] = __builtin_amdgcn_mfma_f32_16x16x32_bf16(A0[kt], B1, acc[0][1], 0, 0, 0);
      acc[1][0] = __builtin_amdgcn_mfma_f32_16x16x32_bf16(A1[kt], B0, acc[1][0], 0, 0, 0);
      acc[1][1] = __builtin_amdgcn_mfma_f32_16x16x32_bf16(A1[kt], B1, acc[1][1], 0, 0, 0);
    }

    // 6. gates (acc reg r == gate r for cell (b,u): i,j,f,o)
    #pragma unroll
    for (int mf2 = 0; mf2 < 2; ++mf2)
      #pragma unroll
      for (int n = 0; n < 2; ++n) {
        f32x4 z = acc[mf2][n];
        float zi = z[0] + bia[mf2][0];
        float zj = z[1] + bia[mf2][1];
        float zf = z[2] + bia[mf2][2];
        float zo = z[3] + bia[mf2][3];
        float cn = cst[mf2][n] * sigf(zf + 1.f) + sigf(zi) * tanhf_(zj);
        float hn = tanhf_(cn) * sigf(zo);
        if (t < lenn[n]) { cst[mf2][n] = cn; hst[mf2][n] = hn; }
        sH[n * 16 + (l & 15)][w * 8 + mf2 * 4 + (l >> 4)] = f2bf(hst[mf2][n]);
      }
    LGKM0; BAR(); SCHED0;

    // 7. pack + coalesced u64 store to L3
    {
      int bbL = tid >> 3, u8 = tid & 7;
      u64 pk = *(const u64*)&sH[bbL][u8 * 4];
      u64* hdst = hbuf + (((lstm * 2 + (t & 1)) * 256) + b0 + bbL) * 128 + (u0 >> 2) + u8;
      __hip_atomic_store(hdst, pk, __ATOMIC_RELAXED, __HIP_MEMORY_SCOPE_AGENT);
    }
    VM0; BAR();   // all waves' stores acked at L3 before arrival

    // 8. group barrier (16 WGs), relaxed agent atomics
    if (tid == 0) {
      __hip_atomic_fetch_add(&bar[grp * 32], 1u, __ATOMIC_RELAXED,
                             __HIP_MEMORY_SCOPE_AGENT);
      unsigned target = 16u * (unsigned)(t + 1);
      while (__hip_atomic_load(&bar[grp * 32], __ATOMIC_RELAXED,
                               __HIP_MEMORY_SCOPE_AGENT) < target)
        __builtin_amdgcn_s_sleep(1);
    }
    BAR(); SCHED0;
  }

  #pragma unroll
  for (int mf2 = 0; mf2 < 2; ++mf2)
    #pragma unroll
    for (int n = 0; n < 2; ++n) {
      int bb = b0 + n * 16 + (l & 15);
      int uu = u0 + w * 8 + mf2 * 4 + (l >> 4);
      hfin[lstm * (256 * 512) + bb * 512 + uu] = hst[mf2][n];
    }
}

__global__ void dense_out(const float* __restrict__ hfin,
                          const float* __restrict__ Wd, const float* __restrict__ bd,
                          float* __restrict__ out) {
  const int b = blockIdx.x, l = threadIdx.x;
  float a0 = 0.f, a1 = 0.f, a2 = 0.f;
  for (int i = l; i < 1024; i += 64) {
    float hv = (i < 512) ? hfin[b * 512 + i] : hfin[256 * 512 + b * 512 + (i - 512)];
    a0 += hv * Wd[i * 3 + 0];
    a1 += hv * Wd[i * 3 + 1];
    a2 += hv * Wd[i * 3 + 2];
  }
  #pragma unroll
  for (int off = 32; off > 0; off >>= 1) {
    a0 += __shfl_down(a0, off);
    a1 += __shfl_down(a1, off);
    a2 += __shfl_down(a2, off);
  }
  if (l == 0) {
    out[b * 3 + 0] = a0 + bd[0];
    out[b * 3 + 1] = a1 + bd[1];
    out[b * 3 + 2] = a2 + bd[2];
  }
}

extern "C" void kernel_launch(void* const* d_in, const int* in_sizes, int n_in,
                              void* d_out, int out_size, void* d_ws, size_t ws_size,
                              hipStream_t stream) {
  const int*   lids = (const int*)d_in[0];
  const int*   rids = (const int*)d_in[1];
  const int*   llen = (const int*)d_in[2];
  const int*   rlen = (const int*)d_in[3];
  const float* emb  = (const float*)d_in[4];
  const float* Wl   = (const float*)d_in[5];
  const float* bl   = (const float*)d_in[6];
  const float* Wr   = (const float*)d_in[7];
  const float* br   = (const float*)d_in[8];
  const float* Wd   = (const float*)d_in[9];
  const float* bd   = (const float*)d_in[10];

  unsigned char* ws = (unsigned char*)d_ws;
  unsigned int* bar = (unsigned int*)ws;             // 16 groups * 128B
  u64*   hbuf = (u64*)(ws + 4096);                   // 1 MiB
  float* hfin = (float*)(ws + 4096 + (1u << 20));    // 1 MiB

  hipMemsetAsync(bar, 0, 2048, stream);              // re-arm barrier each call
  hipLaunchKernelGGL(lstm_persist, dim3(256), dim3(256), 0, stream,
                     lids, rids, llen, rlen, emb, Wl, bl, Wr, br, hbuf, hfin, bar);
  hipLaunchKernelGGL(dense_out, dim3(256), dim3(64), 0, stream,
                     hfin, Wd, bd, (float*)d_out);
}

// Round 6
// 667.856 us; speedup vs baseline: 9.4282x; 1.0761x over previous
//
#include <hip/hip_runtime.h>

// TdLstm: twin BasicLSTM (i,j,f,o; forget_bias=1) + final dense.
// Persistent kernel, 256 WGs. W^T in VGPRs (52 frags/wave, M-split).
// Round-4 verified base + GEMM split: x-part (kt 0-9, depends only on
// prefetched x) runs in the post-arrive shadow; only h-part (kt 10-25) +
// gates + h exchange remain on the serial critical chain.
// ws: [0,2048) barrier counters (memset), [4096,+1MiB) h ping-pong (bf16),
// then 1MiB final h (f32).

using bf16x8 = __attribute__((ext_vector_type(8))) __bf16;
using f32x4  = __attribute__((ext_vector_type(4))) float;
using u32x4  = __attribute__((ext_vector_type(4))) unsigned int;
typedef unsigned short u16;
typedef unsigned long long u64;

#define NT 128
#define ROWB 1664                                  // 832 k-elems * 2B per B-row
#define SWZ(row, off) ((off) ^ (((row) & 7) << 4)) // bank swizzle, 16B granules

#define LGKM0  asm volatile("s_waitcnt lgkmcnt(0)" ::: "memory")
#define VM0    asm volatile("s_waitcnt vmcnt(0)" ::: "memory")
#define BAR()  __builtin_amdgcn_s_barrier()
#define SCHED0 __builtin_amdgcn_sched_barrier(0)

__device__ __forceinline__ u16 f2bf(float f) {
  union { float f; unsigned u; } v; v.f = f;
  unsigned r = v.u + 0x7fffu + ((v.u >> 16) & 1u);
  return (u16)(r >> 16);
}
__device__ __forceinline__ float sigf(float x) { return 1.f / (1.f + __expf(-x)); }
__device__ __forceinline__ float tanhf_(float x) { return 2.f / (1.f + __expf(-2.f * x)) - 1.f; }

// static-index store into A-fragment array (avoid scratch, rule #20)
__device__ __forceinline__ void setA26(bf16x8 (&A)[26], int kt, bf16x8 v) {
  switch (kt) {
    case 0:A[0]=v;break;  case 1:A[1]=v;break;  case 2:A[2]=v;break;
    case 3:A[3]=v;break;  case 4:A[4]=v;break;  case 5:A[5]=v;break;
    case 6:A[6]=v;break;  case 7:A[7]=v;break;  case 8:A[8]=v;break;
    case 9:A[9]=v;break;  case 10:A[10]=v;break; case 11:A[11]=v;break;
    case 12:A[12]=v;break; case 13:A[13]=v;break; case 14:A[14]=v;break;
    case 15:A[15]=v;break; case 16:A[16]=v;break; case 17:A[17]=v;break;
    case 18:A[18]=v;break; case 19:A[19]=v;break; case 20:A[20]=v;break;
    case 21:A[21]=v;break; case 22:A[22]=v;break; case 23:A[23]=v;break;
    case 24:A[24]=v;break; case 25:A[25]=v;break;
  }
}

__global__ __launch_bounds__(256, 1) void lstm_persist(
    const int* __restrict__ lids, const int* __restrict__ rids,
    const int* __restrict__ llen, const int* __restrict__ rlen,
    const float* __restrict__ emb,
    const float* __restrict__ Wl, const float* __restrict__ bl,
    const float* __restrict__ Wr, const float* __restrict__ br,
    u64* __restrict__ hbuf,      // [2 lstm][2 buf][256][128] u64 (bf16 x4)
    float* __restrict__ hfin,    // [2 lstm][256][512] f32
    unsigned int* __restrict__ bar)
{
  __shared__ __align__(16) unsigned char sB[32 * ROWB]; // 52 KiB (also W scratch)
  __shared__ __align__(8)  u16 sH[32][36];              // h-out staging
  __shared__ int sI[4096];                              // ids[32 rows][128 t]

  const int tid = threadIdx.x;
  const int w = tid >> 6, l = tid & 63;
  const int bid = blockIdx.x;
  const int xcd = bid & 7, idx = bid >> 3;
  const int grp = xcd * 2 + (idx >> 4);   // 0..15 (lstm x b-tile)
  const int ct  = idx & 15;               // u-tile: u0 = ct*32
  const int lstm = grp >> 3, bt = grp & 7;
  const int b0 = bt * 32, u0 = ct * 32;

  const int*   ids  = lstm ? rids : lids;
  const int*   lenp = lstm ? rlen : llen;
  const float* W    = lstm ? Wr : Wl;
  const float* bv   = lstm ? br : bl;
  unsigned int* const blp = bar + grp * 32;

  // ---- one-time: build W^T A-fragments (M-split: wave w owns mf=2w,2w+1) ----
  bf16x8 A0[26], A1[26];
  {
    float* sW = (float*)sB;                // [4 g][64 r][32 c] = 32 KiB scratch
    for (int kc = 0; kc < 13; ++kc) {
      for (int i = 0; i < 32; ++i) {
        int id2 = tid + i * 256;
        int c = id2 & 31, r = (id2 >> 5) & 63, g = id2 >> 11;
        int kk = kc * 64 + r;
        float v = 0.f;
        if (kk < 300)       v = W[kk * 2048 + g * 512 + u0 + c];
        else if (kk >= 320) v = W[(kk - 20) * 2048 + g * 512 + u0 + c];
        sW[(g * 64 + r) * 32 + c] = v;
      }
      __syncthreads();
      #pragma unroll
      for (int kt2 = 0; kt2 < 2; ++kt2) {
        int kt = kc * 2 + kt2;
        #pragma unroll
        for (int mf2 = 0; mf2 < 2; ++mf2) {
          int mf = w * 2 + mf2;
          int rho = mf * 16 + (l & 15);    // col map rho = du*4 + g
          int du = rho >> 2, g = rho & 3;
          union { u16 s[8]; bf16x8 v; } tmp;
          #pragma unroll
          for (int j = 0; j < 8; ++j) {
            int kr = kt2 * 32 + ((l >> 4) << 3) + j;
            tmp.s[j] = f2bf(sW[(g * 64 + kr) * 32 + du]);
          }
          if (mf2 == 0) setA26(A0, kt, tmp.v); else setA26(A1, kt, tmp.v);
        }
      }
      __syncthreads();
    }
  }

  // zero-pad x region k in [300,320)
  if (tid < 160) {
    int row = tid / 5, c5 = tid - (tid / 5) * 5;
    *(u64*)(sB + row * ROWB + SWZ(row, 600 + c5 * 8)) = 0ULL;
  }
  // preload ids for this b-tile
  {
    const int* src = ids + b0 * NT;
    #pragma unroll
    for (int i = 0; i < 4; ++i)
      *(int4*)&sI[(tid + i * 256) * 4] = *(const int4*)&src[(tid + i * 256) * 4];
  }

  int ldsoff[10], sirow[10], foff[10];
  #pragma unroll
  for (int i = 0; i < 10; ++i) {
    int id2 = tid + i * 256;
    int row = id2 / 75, f4 = id2 - row * 75;
    ldsoff[i] = row * ROWB + SWZ(row, f4 * 8);
    sirow[i]  = row * NT;
    foff[i]   = f4 * 4;
  }
  int hoff[16];
  #pragma unroll
  for (int i = 0; i < 16; ++i) {
    int id2 = tid + i * 256;
    int row = id2 >> 7, c8 = id2 & 127;
    hoff[i] = row * ROWB + SWZ(row, 640 + c8 * 8);
  }

  int lenn[2];
  lenn[0] = lenp[b0 + (l & 15)];
  lenn[1] = lenp[b0 + 16 + (l & 15)];
  float bia[2][4];
  #pragma unroll
  for (int mf2 = 0; mf2 < 2; ++mf2) {
    int du = w * 8 + mf2 * 4 + (l >> 4);
    #pragma unroll
    for (int g = 0; g < 4; ++g) bia[mf2][g] = bv[g * 512 + u0 + du];
  }
  float cst[2][2] = {{0.f, 0.f}, {0.f, 0.f}};
  float hst[2][2] = {{0.f, 0.f}, {0.f, 0.f}};
  __syncthreads();

  // prologue: stage x(0), prefetch x(1)
  float4 px[10];
  #pragma unroll
  for (int i = 0; i < 10; ++i)
    if (i < 9 || tid < 96) {
      int eid = sI[sirow[i]];
      float4 xv = *(const float4*)(emb + eid * 300 + foff[i]);
      u64 pk = (u64)f2bf(xv.x) | ((u64)f2bf(xv.y) << 16) |
               ((u64)f2bf(xv.z) << 32) | ((u64)f2bf(xv.w) << 48);
      *(u64*)(sB + ldsoff[i]) = pk;
    }
  #pragma unroll
  for (int i = 0; i < 10; ++i)
    if (i < 9 || tid < 96) {
      int eid = sI[sirow[i] + 1];
      px[i] = *(const float4*)(emb + eid * 300 + foff[i]);
    }
  __syncthreads();

  const int r0 = l & 15, r1 = 16 + (l & 15);

  // x-GEMM(0): kt 0..9 (k < 320 region, x + zero pad)
  f32x4 xacc[2][2];
  xacc[0][0] = {0.f,0.f,0.f,0.f}; xacc[0][1] = {0.f,0.f,0.f,0.f};
  xacc[1][0] = {0.f,0.f,0.f,0.f}; xacc[1][1] = {0.f,0.f,0.f,0.f};
  #pragma unroll
  for (int kt = 0; kt < 10; ++kt) {
    int kb = kt * 64 + ((l >> 4) << 4);
    bf16x8 B0 = __builtin_bit_cast(bf16x8, *(const u32x4*)(sB + r0 * ROWB + SWZ(r0, kb)));
    bf16x8 B1 = __builtin_bit_cast(bf16x8, *(const u32x4*)(sB + r1 * ROWB + SWZ(r1, kb)));
    xacc[0][0] = __builtin_amdgcn_mfma_f32_16x16x32_bf16(A0[kt], B0, xacc[0][0], 0, 0, 0);
    xacc[0][1] = __builtin_amdgcn_mfma_f32_16x16x32_bf16(A0[kt], B1, xacc[0][1], 0, 0, 0);
    xacc[1][0] = __builtin_amdgcn_mfma_f32_16x16x32_bf16(A1[kt], B0, xacc[1][0], 0, 0, 0);
    xacc[1][1] = __builtin_amdgcn_mfma_f32_16x16x32_bf16(A1[kt], B1, xacc[1][1], 0, 0, 0);
  }

  for (int t = 0; t < NT; ++t) {
    if (t > 0) {
      // poll barrier(t-1): h(t-1) of all 16 u-tiles visible at L3
      if (tid == 0) {
        unsigned target = 16u * (unsigned)t;
        while (__hip_atomic_load(blp, __ATOMIC_RELAXED, __HIP_MEMORY_SCOPE_AGENT) < target)
          __builtin_amdgcn_s_sleep(1);
      }
      BAR(); SCHED0;
      // h(t-1) loads (L3-coherent) -> LDS
      const u64* hsrc = hbuf + (((lstm * 2 + ((t & 1) ^ 1)) * 256) + b0) * 128;
      u64 hld[16];
      #pragma unroll
      for (int i = 0; i < 16; ++i)
        hld[i] = __hip_atomic_load(&hsrc[tid + i * 256], __ATOMIC_RELAXED,
                                   __HIP_MEMORY_SCOPE_AGENT);
      #pragma unroll
      for (int i = 0; i < 16; ++i) *(u64*)(sB + hoff[i]) = hld[i];
      LGKM0; BAR(); SCHED0;
      // h-GEMM: kt 10..25 (k in [320,832), the h rows), accumulate into xacc
      #pragma unroll
      for (int kt = 10; kt < 26; ++kt) {
        int kb = kt * 64 + ((l >> 4) << 4);
        bf16x8 B0 = __builtin_bit_cast(bf16x8, *(const u32x4*)(sB + r0 * ROWB + SWZ(r0, kb)));
        bf16x8 B1 = __builtin_bit_cast(bf16x8, *(const u32x4*)(sB + r1 * ROWB + SWZ(r1, kb)));
        xacc[0][0] = __builtin_amdgcn_mfma_f32_16x16x32_bf16(A0[kt], B0, xacc[0][0], 0, 0, 0);
        xacc[0][1] = __builtin_amdgcn_mfma_f32_16x16x32_bf16(A0[kt], B1, xacc[0][1], 0, 0, 0);
        xacc[1][0] = __builtin_amdgcn_mfma_f32_16x16x32_bf16(A1[kt], B0, xacc[1][0], 0, 0, 0);
        xacc[1][1] = __builtin_amdgcn_mfma_f32_16x16x32_bf16(A1[kt], B1, xacc[1][1], 0, 0, 0);
      }
    }

    // gates (acc reg r == gate r for cell (b,u): i,j,f,o)
    #pragma unroll
    for (int mf2 = 0; mf2 < 2; ++mf2)
      #pragma unroll
      for (int n = 0; n < 2; ++n) {
        f32x4 z = xacc[mf2][n];
        float zi = z[0] + bia[mf2][0];
        float zj = z[1] + bia[mf2][1];
        float zf = z[2] + bia[mf2][2];
        float zo = z[3] + bia[mf2][3];
        float cn = cst[mf2][n] * sigf(zf + 1.f) + sigf(zi) * tanhf_(zj);
        float hn = tanhf_(cn) * sigf(zo);
        if (t < lenn[n]) { cst[mf2][n] = cn; hst[mf2][n] = hn; }
        sH[n * 16 + (l & 15)][w * 8 + mf2 * 4 + (l >> 4)] = f2bf(hst[mf2][n]);
      }
    LGKM0; BAR(); SCHED0;

    // pack + coalesced u64 store of h(t) to L3
    {
      int bbL = tid >> 3, u8 = tid & 7;
      u64 pk = *(const u64*)&sH[bbL][u8 * 4];
      u64* hdst = hbuf + (((lstm * 2 + (t & 1)) * 256) + b0 + bbL) * 128 + (u0 >> 2) + u8;
      __hip_atomic_store(hdst, pk, __ATOMIC_RELAXED, __HIP_MEMORY_SCOPE_AGENT);
    }
    // stage x(t+1) from px regs into LDS (hides under store-ack)
    #pragma unroll
    for (int i = 0; i < 10; ++i)
      if (i < 9 || tid < 96) {
        float4 xv = px[i];
        u64 pk = (u64)f2bf(xv.x) | ((u64)f2bf(xv.y) << 16) |
                 ((u64)f2bf(xv.z) << 32) | ((u64)f2bf(xv.w) << 48);
        *(u64*)(sB + ldsoff[i]) = pk;
      }
    VM0; LGKM0; BAR();   // stores acked at L3 + x staged, all waves

    // arrive
    if (tid == 0)
      __hip_atomic_fetch_add(blp, 1u, __ATOMIC_RELAXED, __HIP_MEMORY_SCOPE_AGENT);
    SCHED0;

    // prefetch x(t+2) (consumed next tail -> latency fully hidden)
    {
      int tn2 = (t + 2) & (NT - 1);
      #pragma unroll
      for (int i = 0; i < 10; ++i)
        if (i < 9 || tid < 96) {
          int eid = sI[sirow[i] + tn2];
          px[i] = *(const float4*)(emb + eid * 300 + foff[i]);
        }
    }
    // x-GEMM(t+1): kt 0..9 into fresh xacc (in the barrier-skew shadow)
    xacc[0][0] = {0.f,0.f,0.f,0.f}; xacc[0][1] = {0.f,0.f,0.f,0.f};
    xacc[1][0] = {0.f,0.f,0.f,0.f}; xacc[1][1] = {0.f,0.f,0.f,0.f};
    #pragma unroll
    for (int kt = 0; kt < 10; ++kt) {
      int kb = kt * 64 + ((l >> 4) << 4);
      bf16x8 B0 = __builtin_bit_cast(bf16x8, *(const u32x4*)(sB + r0 * ROWB + SWZ(r0, kb)));
      bf16x8 B1 = __builtin_bit_cast(bf16x8, *(const u32x4*)(sB + r1 * ROWB + SWZ(r1, kb)));
      xacc[0][0] = __builtin_amdgcn_mfma_f32_16x16x32_bf16(A0[kt], B0, xacc[0][0], 0, 0, 0);
      xacc[0][1] = __builtin_amdgcn_mfma_f32_16x16x32_bf16(A0[kt], B1, xacc[0][1], 0, 0, 0);
      xacc[1][0] = __builtin_amdgcn_mfma_f32_16x16x32_bf16(A1[kt], B0, xacc[1][0], 0, 0, 0);
      xacc[1][1] = __builtin_amdgcn_mfma_f32_16x16x32_bf16(A1[kt], B1, xacc[1][1], 0, 0, 0);
    }
  }

  #pragma unroll
  for (int mf2 = 0; mf2 < 2; ++mf2)
    #pragma unroll
    for (int n = 0; n < 2; ++n) {
      int bb = b0 + n * 16 + (l & 15);
      int uu = u0 + w * 8 + mf2 * 4 + (l >> 4);
      hfin[lstm * (256 * 512) + bb * 512 + uu] = hst[mf2][n];
    }
}

__global__ void dense_out(const float* __restrict__ hfin,
                          const float* __restrict__ Wd, const float* __restrict__ bd,
                          float* __restrict__ out) {
  const int b = blockIdx.x, l = threadIdx.x;
  float a0 = 0.f, a1 = 0.f, a2 = 0.f;
  for (int i = l; i < 1024; i += 64) {
    float hv = (i < 512) ? hfin[b * 512 + i] : hfin[256 * 512 + b * 512 + (i - 512)];
    a0 += hv * Wd[i * 3 + 0];
    a1 += hv * Wd[i * 3 + 1];
    a2 += hv * Wd[i * 3 + 2];
  }
  #pragma unroll
  for (int off = 32; off > 0; off >>= 1) {
    a0 += __shfl_down(a0, off);
    a1 += __shfl_down(a1, off);
    a2 += __shfl_down(a2, off);
  }
  if (l == 0) {
    out[b * 3 + 0] = a0 + bd[0];
    out[b * 3 + 1] = a1 + bd[1];
    out[b * 3 + 2] = a2 + bd[2];
  }
}

extern "C" void kernel_launch(void* const* d_in, const int* in_sizes, int n_in,
                              void* d_out, int out_size, void* d_ws, size_t ws_size,
                              hipStream_t stream) {
  const int*   lids = (const int*)d_in[0];
  const int*   rids = (const int*)d_in[1];
  const int*   llen = (const int*)d_in[2];
  const int*   rlen = (const int*)d_in[3];
  const float* emb  = (const float*)d_in[4];
  const float* Wl   = (const float*)d_in[5];
  const float* bl   = (const float*)d_in[6];
  const float* Wr   = (const float*)d_in[7];
  const float* br   = (const float*)d_in[8];
  const float* Wd   = (const float*)d_in[9];
  const float* bd   = (const float*)d_in[10];

  unsigned char* ws = (unsigned char*)d_ws;
  unsigned int* bar = (unsigned int*)ws;             // 16 groups * 128B
  u64*   hbuf = (u64*)(ws + 4096);                   // 1 MiB
  float* hfin = (float*)(ws + 4096 + (1u << 20));    // 1 MiB

  hipMemsetAsync(bar, 0, 2048, stream);              // re-arm barrier each call
  hipLaunchKernelGGL(lstm_persist, dim3(256), dim3(256), 0, stream,
                     lids, rids, llen, rlen, emb, Wl, bl, Wr, br, hbuf, hfin, bar);
  hipLaunchKernelGGL(dense_out, dim3(256), dim3(64), 0, stream,
                     hfin, Wd, bd, (float*)d_out);
}